// Round 1
// baseline (74.780 us; speedup 1.0000x reference)
//
#include <hip/hip_runtime.h>

// Problem constants (from reference)
constexpr int NI      = 64;   // instances
constexpr int MM      = 28;   // mask resolution
constexpr int THING_C = 80;
constexpr int STUFF_C = 53;
constexpr int HH      = 512;
constexpr int WW      = 800;

// One block per (instance n, row y). 256 threads:
//  - lanes 0..27 build the y-interpolated mask row fy[28] in LDS
//  - lanes 0..199 each emit one float4 (4 px) of the 800-px output row
__global__ __launch_bounds__(256) void thing_kernel(
    const float* __restrict__ mask_logits,   // [64][80][28][28]
    const float* __restrict__ sem_seg,       // [133][512][800]
    const float* __restrict__ bboxes,        // [64][4]
    const int*   __restrict__ cls_idx,       // [64]
    float*       __restrict__ out)           // [117][512][800]
{
    const int y = blockIdx.x;   // 0..511
    const int n = blockIdx.y;   // 0..63

    const int   cls = cls_idx[n];
    const float bx1 = bboxes[n * 4 + 0];
    const float by1 = bboxes[n * 4 + 1];
    const float bx2 = bboxes[n * 4 + 2];
    const float by2 = bboxes[n * 4 + 3];

    const int x0 = (int)floorf(bx1);
    const int y0 = (int)floorf(by1);
    const int x2 = (int)floorf(bx2);
    const int y2 = (int)floorf(by2);
    const float bwf = (float)(x2 - x0 + 1);
    const float bhf = (float)(y2 - y0 + 1);

    // mask-paste row validity: max(y0,0) <= y < min(y2+1, H)
    const bool row_in = (y >= max(y0, 0)) && (y < min(y2 + 1, HH));

    // crop box (jnp.round == rint, half-to-even)
    const int cy1 = y0;
    const int cy2 = (int)rintf(by2) + 1;
    const int cx1 = x0;
    const int cx2 = (int)rintf(bx2) + 1;
    const bool crow_in = (y >= cy1) && (y < cy2);

    __shared__ float fy_row[MM];
    if (row_in) {
        // src_y = clip((y - y0 + 0.5) * M / bh - 0.5, 0, M-1)  (same op order as ref)
        float sy = ((float)y - (float)y0 + 0.5f) * (float)MM / bhf - 0.5f;
        sy = fminf(fmaxf(sy, 0.0f), (float)(MM - 1));
        const int   iy0 = (int)floorf(sy);
        const int   iy1 = min(iy0 + 1, MM - 1);
        const float ly  = sy - (float)iy0;
        if (threadIdx.x < MM) {
            const float* msk = mask_logits + (((size_t)n * THING_C + cls) * (MM * MM));
            fy_row[threadIdx.x] = msk[iy0 * MM + threadIdx.x] * (1.0f - ly)
                                + msk[iy1 * MM + threadIdx.x] * ly;
        }
    }
    __syncthreads();

    const int t = threadIdx.x;
    if (t >= WW / 4) return;          // 200 active lanes
    const int xbase = t * 4;

    const float* sem_row = sem_seg + (((size_t)(STUFF_C + cls) * HH + y) * WW);
    float*       out_row = out     + (((size_t)(STUFF_C + n)   * HH + y) * WW);

    const int xin_lo = max(x0, 0);
    const int xin_hi = min(x2 + 1, WW);

    float4 v;
    float* vp = reinterpret_cast<float*>(&v);
#pragma unroll
    for (int j = 0; j < 4; ++j) {
        const int x = xbase + j;
        float val = 0.0f;
        if (row_in && x >= xin_lo && x < xin_hi) {
            float sx = ((float)x - (float)x0 + 0.5f) * (float)MM / bwf - 0.5f;
            sx = fminf(fmaxf(sx, 0.0f), (float)(MM - 1));
            const int   ix0 = (int)floorf(sx);
            const int   ix1 = min(ix0 + 1, MM - 1);
            const float lx  = sx - (float)ix0;
            val = fy_row[ix0] * (1.0f - lx) + fy_row[ix1] * lx;
        }
        if (crow_in && x >= cx1 && x < cx2) {
            val += sem_row[x];
        }
        vp[j] = val;
    }
    *reinterpret_cast<float4*>(out_row + xbase) = v;
}

extern "C" void kernel_launch(void* const* d_in, const int* in_sizes, int n_in,
                              void* d_out, int out_size, void* d_ws, size_t ws_size,
                              hipStream_t stream) {
    const float* mask_logits = (const float*)d_in[0];  // 64*80*28*28
    const float* sem_seg     = (const float*)d_in[1];  // 133*512*800
    const float* bboxes      = (const float*)d_in[2];  // 64*4
    const int*   cls_idx     = (const int*)d_in[3];    // 64
    float*       out         = (float*)d_out;          // 117*512*800

    // Stuff channels: sem_seg_logits[0,:53] is the leading contiguous block;
    // output channels 0..52 are the leading block of d_out -> one D2D copy.
    hipMemcpyAsync(out, sem_seg, (size_t)STUFF_C * HH * WW * sizeof(float),
                   hipMemcpyDeviceToDevice, stream);

    // Thing channels: one block per (row, instance).
    dim3 grid(HH, NI);
    thing_kernel<<<grid, 256, 0, stream>>>(mask_logits, sem_seg, bboxes, cls_idx, out);
}

// Round 2
// 64.200 us; speedup vs baseline: 1.1648x; 1.1648x over previous
//
#include <hip/hip_runtime.h>

// Problem constants (from reference)
constexpr int NI      = 64;   // instances
constexpr int MM      = 28;   // mask resolution
constexpr int THING_C = 80;
constexpr int STUFF_C = 53;
constexpr int HH      = 512;
constexpr int WW      = 800;

// One block per output row (c, y). c in [0,117).
//  c < 53 : stuff channel -> verbatim row copy from sem_seg[c]
//  c >= 53: thing instance n = c-53 -> bilinear mask paste + cropped sem add
// Block = 256 threads; lanes 0..199 each handle one float4 (4 px) of the row.
__global__ __launch_bounds__(256) void pan_kernel(
    const float* __restrict__ mask_logits,   // [64][80][28][28]
    const float* __restrict__ sem_seg,       // [133][512][800]
    const float* __restrict__ bboxes,        // [64][4]
    const int*   __restrict__ cls_idx,       // [64]
    float*       __restrict__ out)           // [117][512][800]
{
    const int y = blockIdx.x;   // 0..511
    const int c = blockIdx.y;   // 0..116
    const int t = threadIdx.x;

    if (c < STUFF_C) {
        // ---- stuff: contiguous row copy (block-uniform branch) ----
        if (t < WW / 4) {
            const float4* src = reinterpret_cast<const float4*>(
                sem_seg + ((size_t)c * HH + y) * WW);
            float4* dst = reinterpret_cast<float4*>(
                out + ((size_t)c * HH + y) * WW);
            dst[t] = src[t];
        }
        return;
    }

    // ---- thing channel ----
    const int n   = c - STUFF_C;
    const int cls = cls_idx[n];
    const float bx1 = bboxes[n * 4 + 0];
    const float by1 = bboxes[n * 4 + 1];
    const float bx2 = bboxes[n * 4 + 2];
    const float by2 = bboxes[n * 4 + 3];

    const int x0 = (int)floorf(bx1);
    const int y0 = (int)floorf(by1);
    const int x2 = (int)floorf(bx2);
    const int y2 = (int)floorf(by2);
    const float bwf = (float)(x2 - x0 + 1);
    const float bhf = (float)(y2 - y0 + 1);

    // mask-paste row validity: max(y0,0) <= y < min(y2+1, H)
    const bool row_in = (y >= max(y0, 0)) && (y < min(y2 + 1, HH));

    // crop box (jnp.round == rint, half-to-even)
    const int cy2 = (int)rintf(by2) + 1;
    const int cx1 = x0;
    const int cx2 = (int)rintf(bx2) + 1;
    const bool crow_in = (y >= y0) && (y < cy2);

    __shared__ float fy_row[MM];
    if (row_in) {
        // src_y = clip((y - y0 + 0.5) * M / bh - 0.5, 0, M-1)  (ref op order)
        float sy = ((float)y - (float)y0 + 0.5f) * (float)MM / bhf - 0.5f;
        sy = fminf(fmaxf(sy, 0.0f), (float)(MM - 1));
        const int   iy0 = (int)floorf(sy);
        const int   iy1 = min(iy0 + 1, MM - 1);
        const float ly  = sy - (float)iy0;
        if (t < MM) {
            const float* msk = mask_logits + (((size_t)n * THING_C + cls) * (MM * MM));
            fy_row[t] = msk[iy0 * MM + t] * (1.0f - ly)
                      + msk[iy1 * MM + t] * ly;
        }
    }
    __syncthreads();

    if (t >= WW / 4) return;          // 200 active lanes
    const int xbase = t * 4;

    const float* sem_row = sem_seg + (((size_t)(STUFF_C + cls) * HH + y) * WW);
    float*       out_row = out     + (((size_t)c               * HH + y) * WW);

    const int xin_lo = max(x0, 0);
    const int xin_hi = min(x2 + 1, WW);

    float4 v;
    float* vp = reinterpret_cast<float*>(&v);
#pragma unroll
    for (int j = 0; j < 4; ++j) {
        const int x = xbase + j;
        float val = 0.0f;
        if (row_in && x >= xin_lo && x < xin_hi) {
            float sx = ((float)x - (float)x0 + 0.5f) * (float)MM / bwf - 0.5f;
            sx = fminf(fmaxf(sx, 0.0f), (float)(MM - 1));
            const int   ix0 = (int)floorf(sx);
            const int   ix1 = min(ix0 + 1, MM - 1);
            const float lx  = sx - (float)ix0;
            val = fy_row[ix0] * (1.0f - lx) + fy_row[ix1] * lx;
        }
        if (crow_in && x >= cx1 && x < cx2) {
            val += sem_row[x];
        }
        vp[j] = val;
    }
    *reinterpret_cast<float4*>(out_row + xbase) = v;
}

extern "C" void kernel_launch(void* const* d_in, const int* in_sizes, int n_in,
                              void* d_out, int out_size, void* d_ws, size_t ws_size,
                              hipStream_t stream) {
    const float* mask_logits = (const float*)d_in[0];  // 64*80*28*28
    const float* sem_seg     = (const float*)d_in[1];  // 133*512*800
    const float* bboxes      = (const float*)d_in[2];  // 64*4
    const int*   cls_idx     = (const int*)d_in[3];    // 64
    float*       out         = (float*)d_out;          // 117*512*800

    dim3 grid(HH, STUFF_C + NI);   // (512, 117) -> one block per output row
    pan_kernel<<<grid, 256, 0, stream>>>(mask_logits, sem_seg, bboxes, cls_idx, out);
}